// Round 2
// baseline (460.078 us; speedup 1.0000x reference)
//
#include <hip/hip_runtime.h>
#include <math.h>

#define NN 8192
#define GG 32
#define SS 256
#define TILE 64

typedef float v4f __attribute__((ext_vector_type(4)));

// Swizzled flat index for logical element (x,y) of a [64][64] f32 tile.
// Rows are 256 B apart (16B-aligned quads); XOR of the row bits into the
// column quad spreads transposed scalar writes across 8 banks (2-way = free)
// and keeps row-quad reads contiguous (ds_read_b128, conflict-free).
#define SWZ(x, y) (((x) << 6) + ((y) ^ ((x) & 0x3C)))

// bh[i,j] = exp((sim[i,j] - m[i,gJ])/tau) / l[i,gJ]
// out[i,j] = bh[i,j]*bh[j,i] = exp((sim[i,j]+sim[j,i])/tau - c[i,gJ] - c[j,gI])
// with c[i,g] = m[i,g]/tau + ln(l[i,g]).  out is SYMMETRIC: tile (J,I) is the
// transpose of tile (I,J) — compute once, transpose through LDS.

// Pass 1: one wave per (row, group). 256 floats/wave via float4, shuffle-reduce.
// Side effect: streams all 256 MB of sim through L3, leaving it resident.
__global__ __launch_bounds__(256) void bh_stats(const float* __restrict__ sim,
                                                float* __restrict__ cst) {
    const int wave = threadIdx.x >> 6;
    const int lane = threadIdx.x & 63;
    const int flat = blockIdx.x * 4 + wave;   // flat = row*GG + g
    const int row  = flat >> 5;               // /GG
    const int g    = flat & (GG - 1);
    const int jbase = g * SS + lane * 4;

    const float4 v = *(const float4*)(sim + (size_t)row * NN + jbase);
    const float x0 = (jbase + 0 == row) ? -INFINITY : v.x;
    const float x1 = (jbase + 1 == row) ? -INFINITY : v.y;
    const float x2 = (jbase + 2 == row) ? -INFINITY : v.z;
    const float x3 = (jbase + 3 == row) ? -INFINITY : v.w;

    float m = fmaxf(fmaxf(x0, x1), fmaxf(x2, x3));
#pragma unroll
    for (int off = 32; off >= 1; off >>= 1)
        m = fmaxf(m, __shfl_xor(m, off, 64));

    const float invt = 10.0f;  // 1/TAU
    float s = __expf((x0 - m) * invt) + __expf((x1 - m) * invt)
            + __expf((x2 - m) * invt) + __expf((x3 - m) * invt);
#pragma unroll
    for (int off = 32; off >= 1; off >>= 1)
        s += __shfl_xor(s, off, 64);

    if (lane == 0)
        cst[flat] = m * invt + __logf(s);
}

// Pass 2: triangular grid of tile-pairs (bi,bj), bi<=bj. Each 256-thread block
// stages sim(J,I) transposed into one swizzled LDS tile, computes the (I,J)
// output tile ONCE (one exp per element), stores it NT, then transposes the
// RESULT through the same LDS buffer to emit the (J,I) tile. Single 16 KB
// buffer -> 8 blocks/CU.
__global__ __launch_bounds__(256) void bh_combine(const float* __restrict__ sim,
                                                  const float* __restrict__ cst,
                                                  float* __restrict__ out) {
    // Decode triangular index: M=128 tiles/dim, start(i) = i*(257-i)/2.
    const int M = NN / TILE;
    const int f = blockIdx.x;
    int bi = (int)floorf((257.0f - sqrtf((float)(66049 - 8 * f))) * 0.5f);
    while (bi * (2 * M + 1 - bi) / 2 > f) --bi;
    while ((bi + 1) * (2 * M + 1 - (bi + 1)) / 2 <= f) ++bi;
    const int bj = bi + (f - bi * (2 * M + 1 - bi) / 2);

    __shared__ alignas(16) float T[TILE * TILE];   // Bt, then reused as Ot
    __shared__ alignas(16) float cA[TILE];
    __shared__ alignas(16) float cB[TILE];

    const int I = bi * TILE, J = bj * TILE;
    const int gI = I / SS, gJ = J / SS;
    const int t = threadIdx.x;
    const int c  = (t & 15) << 2;   // col quad within tile (fixed per thread)
    const int r0 = t >> 4;          // row within a 16-row band

    if (t < TILE)            cA[t]        = cst[(I + t) * GG + gJ];
    else if (t < 2 * TILE)   cB[t - TILE] = cst[(J + (t - TILE)) * GG + gI];

    // Stage B = sim(J..J+64, I..I+64) TRANSPOSED into T: T[x][y] = B[y][x].
    // Scalar writes land 2-way per bank (free); A stays in registers.
    float4 a[4];
#pragma unroll
    for (int k = 0; k < 4; ++k) {
        const int r = r0 + 16 * k;
        a[k] = *(const float4*)(sim + (size_t)(I + r) * NN + J + c);
        const float4 b = *(const float4*)(sim + (size_t)(J + r) * NN + I + c);
        T[SWZ(c + 0, r)] = b.x;
        T[SWZ(c + 1, r)] = b.y;
        T[SWZ(c + 2, r)] = b.z;
        T[SWZ(c + 3, r)] = b.w;
    }
    __syncthreads();

    const float invt = 10.0f;  // 1/TAU
    const bool diag = (bi == bj);
    v4f o[4];
#pragma unroll
    for (int k = 0; k < 4; ++k) {
        const int r = r0 + 16 * k;
        const float ca = cA[r];
        const v4f bt = *(const v4f*)&T[SWZ(r, c)];   // sim[J+c+i][I+r], i=0..3
        const v4f cb = *(const v4f*)&cB[c];
        o[k].x = __expf((a[k].x + bt.x) * invt - ca - cb.x);
        o[k].y = __expf((a[k].y + bt.y) * invt - ca - cb.y);
        o[k].z = __expf((a[k].z + bt.z) * invt - ca - cb.z);
        o[k].w = __expf((a[k].w + bt.w) * invt - ca - cb.w);
        if (diag) {   // block-uniform branch: only 128 of 8256 blocks pay this
            if (r == c + 0) o[k].x = 0.0f;
            if (r == c + 1) o[k].y = 0.0f;
            if (r == c + 2) o[k].z = 0.0f;
            if (r == c + 3) o[k].w = 0.0f;
        }
        __builtin_nontemporal_store(o[k], (v4f*)(out + (size_t)(I + r) * NN + J + c));
    }
    if (diag) return;   // diagonal tile is its own transpose

    // out is symmetric: tile (J,I) = transpose of the o-tile just computed.
    // Round-trip the RESULT through T (reuse) instead of recomputing exps.
    __syncthreads();    // everyone done reading T as Bt
#pragma unroll
    for (int k = 0; k < 4; ++k) {
        const int r = r0 + 16 * k;
        T[SWZ(c + 0, r)] = o[k].x;
        T[SWZ(c + 1, r)] = o[k].y;
        T[SWZ(c + 2, r)] = o[k].z;
        T[SWZ(c + 3, r)] = o[k].w;
    }
    __syncthreads();
#pragma unroll
    for (int k = 0; k < 4; ++k) {
        const int r = r0 + 16 * k;
        const v4f p = *(const v4f*)&T[SWZ(r, c)];    // o[c+i][r] = out(J+r, I+c+i)
        __builtin_nontemporal_store(p, (v4f*)(out + (size_t)(J + r) * NN + I + c));
    }
}

extern "C" void kernel_launch(void* const* d_in, const int* in_sizes, int n_in,
                              void* d_out, int out_size, void* d_ws, size_t ws_size,
                              hipStream_t stream) {
    const float* sim = (const float*)d_in[0];
    float* out = (float*)d_out;
    float* cst = (float*)d_ws;  // NN*GG floats = 1 MB of scratch

    // Pass 1: 8192*32 wave-tasks, 4 waves (256 thr) per block.
    bh_stats<<<dim3(NN * GG / 4), dim3(256), 0, stream>>>(sim, cst);
    // Pass 2: triangular tile grid, M*(M+1)/2 = 8256 blocks.
    const int M = NN / TILE;
    bh_combine<<<dim3(M * (M + 1) / 2), dim3(256), 0, stream>>>(sim, cst, out);
}